// Round 2
// baseline (453.933 us; speedup 1.0000x reference)
//
#include <hip/hip_runtime.h>

// ROI Align (FPN multi-level), OUT=7, sampling ratio=2.
// CPT channels per thread: weights/offsets for (m,py,px) are identical across
// channels (only plane base shifts by H*W), so compute the 16 (offset,weight)
// pairs once and reuse for CPT planes. 4x loads in flight, 4x less weight math.

#define NCH 256
#define POOL 7
#define CPT 4

__global__ __launch_bounds__(256) void roi_align_kernel(
    const float* __restrict__ f0, const float* __restrict__ f1,
    const float* __restrict__ f2, const float* __restrict__ f3,
    const float* __restrict__ boxes, const int* __restrict__ bidx,
    float* __restrict__ out, int M)
{
    const int NCG = NCH / CPT;                 // 64 channel groups
    int idx = blockIdx.x * 256 + threadIdx.x;
    int total = M * NCG * POOL * POOL;
    if (idx >= total) return;

    int px = idx % POOL;
    int py = (idx / POOL) % POOL;
    int cg = (idx / (POOL * POOL)) % NCG;
    int m  = idx / (POOL * POOL * NCG);

    float bx0 = boxes[4 * m + 0];
    float by0 = boxes[4 * m + 1];
    float bx1 = boxes[4 * m + 2];
    float by1 = boxes[4 * m + 3];

    // ---- level assignment (matches _assign_levels) ----
    float area = (bx1 - bx0) * (by1 - by0);
    float sz   = sqrtf(area);
    float lvlf = floorf(4.0f + log2f(sz / 224.0f + 1e-8f));
    lvlf = fminf(fmaxf(lvlf, 2.0f), 5.0f);
    int lvl = (int)lvlf - 2;

    const float* fp; int H; int W; float scale;
    if (lvl == 0)      { fp = f0; H = 200; W = 304; scale = 0.25f;    }
    else if (lvl == 1) { fp = f1; H = 100; W = 152; scale = 0.125f;   }
    else if (lvl == 2) { fp = f2; H = 50;  W = 76;  scale = 0.0625f;  }
    else               { fp = f3; H = 25;  W = 38;  scale = 0.03125f; }

    int b = bidx[m];

    // ---- box -> feature coords (matches _roi_align) ----
    float x0 = bx0 * scale - 0.5f;
    float y0 = by0 * scale - 0.5f;
    float x1 = bx1 * scale - 0.5f;
    float y1 = by1 * scale - 0.5f;
    float bin_w = (x1 - x0) * (1.0f / 7.0f);
    float bin_h = (y1 - y0) * (1.0f / 7.0f);

    // ---- axis weights: 4 rows (ylo/yhi for sy=0,1), 4 cols ----
    int   ry[4];  float wy[4];
    int   cx4[4]; float wx[4];
    #pragma unroll
    for (int s = 0; s < 2; ++s) {
        {
            float yy    = y0 + bin_h * ((float)py + 0.25f + 0.5f * (float)s);
            float vy    = (yy >= -1.0f && yy <= (float)H) ? 1.0f : 0.0f;
            float cyv   = fmaxf(yy, 0.0f);
            float ylo_f = floorf(cyv);
            bool  cap   = ylo_f >= (float)(H - 1);
            int   ylo   = cap ? (H - 1) : (int)ylo_f;
            int   yhi   = cap ? (H - 1) : (ylo + 1);
            float l     = cap ? 0.0f : (cyv - ylo_f);
            ry[2 * s + 0] = ylo;  wy[2 * s + 0] = (1.0f - l) * vy;
            ry[2 * s + 1] = yhi;  wy[2 * s + 1] = l * vy;
        }
        {
            float xx    = x0 + bin_w * ((float)px + 0.25f + 0.5f * (float)s);
            float vx    = (xx >= -1.0f && xx <= (float)W) ? 1.0f : 0.0f;
            float cxv   = fmaxf(xx, 0.0f);
            float xlo_f = floorf(cxv);
            bool  cap   = xlo_f >= (float)(W - 1);
            int   xlo   = cap ? (W - 1) : (int)xlo_f;
            int   xhi   = cap ? (W - 1) : (xlo + 1);
            float l     = cap ? 0.0f : (cxv - xlo_f);
            cx4[2 * s + 0] = xlo;  wx[2 * s + 0] = (1.0f - l) * vx;
            cx4[2 * s + 1] = xhi;  wx[2 * s + 1] = l * vx;
        }
    }

    // ---- 16 (offset, weight) pairs shared by all CPT channels ----
    int   off[16];
    float wgt[16];
    #pragma unroll
    for (int i = 0; i < 4; ++i)
        #pragma unroll
        for (int j = 0; j < 4; ++j) {
            off[i * 4 + j] = ry[i] * W + cx4[j];
            wgt[i * 4 + j] = wy[i] * wx[j];
        }

    int c0 = cg * CPT;
    size_t HW = (size_t)(H * W);
    const float* base0 = fp + ((size_t)b * NCH + c0) * HW;

    float acc[CPT];
    #pragma unroll
    for (int cc = 0; cc < CPT; ++cc) {
        const float* base = base0 + (size_t)cc * HW;
        float a = 0.0f;
        #pragma unroll
        for (int k = 0; k < 16; ++k)
            a = fmaf(base[off[k]], wgt[k], a);
        acc[cc] = a * 0.25f;
    }

    float* op = out + ((size_t)m * NCH + c0) * (POOL * POOL) + py * POOL + px;
    #pragma unroll
    for (int cc = 0; cc < CPT; ++cc)
        op[cc * (POOL * POOL)] = acc[cc];
}

extern "C" void kernel_launch(void* const* d_in, const int* in_sizes, int n_in,
                              void* d_out, int out_size, void* d_ws, size_t ws_size,
                              hipStream_t stream) {
    const float* f0    = (const float*)d_in[0];
    const float* f1    = (const float*)d_in[1];
    const float* f2    = (const float*)d_in[2];
    const float* f3    = (const float*)d_in[3];
    const float* boxes = (const float*)d_in[4];
    const int*   bidx  = (const int*)d_in[5];
    float* out = (float*)d_out;

    int M = in_sizes[4] / 4;
    int total = M * (NCH / CPT) * POOL * POOL;
    int blocks = (total + 255) / 256;
    hipLaunchKernelGGL(roi_align_kernel, dim3(blocks), dim3(256), 0, stream,
                       f0, f1, f2, f3, boxes, bidx, out, M);
}